// Round 1
// baseline (1880.832 us; speedup 1.0000x reference)
//
#include <hip/hip_runtime.h>
#include <stdint.h>

// Problem constants
#define M_ROWS 8192    // B*S = 4*2048
#define N_OUT  11008
#define K_IN   4096
#define RANK   192

typedef __attribute__((ext_vector_type(8))) short bf16x8;   // 8 bf16 = 4 VGPRs
typedef __attribute__((ext_vector_type(4))) float f32x4;

// async global->LDS, 16B per lane. LDS dst = wave-uniform base + lane*16.
#define GLDS16(g, l) __builtin_amdgcn_global_load_lds( \
    (const __attribute__((address_space(1))) unsigned int*)(g), \
    (__attribute__((address_space(3))) unsigned int*)(l), 16, 0, 0)

// RTNE float -> bf16 bits (matches __float2bfloat16 for finite values)
static __device__ __forceinline__ unsigned short f2bf(float f) {
    union { float f; unsigned int u; } a; a.f = f;
    unsigned int u = a.u;
    u += 0x7fffu + ((u >> 16) & 1u);
    return (unsigned short)(u >> 16);
}

// ---------------------------------------------------------------------------
// Pass 1: wq = weight + Bd @ Bu  (f32), plus per-(row, colblock) min/max.
// Tile: 64 rows x 256 cols, K=192. 256 thr = 32(tx) x 8(ty); 8x8 per thread.
// grid (11008/64=172, 4096/256=16)
// ---------------------------------------------------------------------------
__global__ __launch_bounds__(256) void k_delta_minmax(
    const float* __restrict__ Wg, const float* __restrict__ Bd,
    const float* __restrict__ Bu, float* __restrict__ wq,
    float* __restrict__ pmin, float* __restrict__ pmax)
{
    __shared__ float bdT[RANK][68];   // transposed Bd tile, pad 64->68 (16B-aligned rows, no bank hot-spot)
    __shared__ float buS[8][256];     // Bu K-chunk
    const int t  = threadIdx.x;
    const int tx = t & 31, ty = t >> 5;
    const int row0 = blockIdx.x * 64;
    const int col0 = blockIdx.y * 256;

    for (int i = t; i < 64 * RANK; i += 256) {
        int r = i / RANK, k = i - r * RANK;
        bdT[k][r] = Bd[(size_t)(row0 + r) * RANK + k];
    }

    float acc[8][8];
#pragma unroll
    for (int a = 0; a < 8; ++a)
#pragma unroll
        for (int b = 0; b < 8; ++b) acc[a][b] = 0.0f;

    for (int kc = 0; kc < RANK / 8; ++kc) {
        __syncthreads();
#pragma unroll
        for (int j = 0; j < 8; ++j)
            buS[j][t] = Bu[(size_t)(kc * 8 + j) * K_IN + col0 + t];
        __syncthreads();
#pragma unroll
        for (int k = 0; k < 8; ++k) {
            float bd[8], bu[8];
#pragma unroll
            for (int rr = 0; rr < 8; ++rr) bd[rr] = bdT[kc * 8 + k][ty * 8 + rr];
#pragma unroll
            for (int cc = 0; cc < 8; ++cc) bu[cc] = buS[k][tx + 32 * cc];
#pragma unroll
            for (int rr = 0; rr < 8; ++rr)
#pragma unroll
                for (int cc = 0; cc < 8; ++cc)
                    acc[rr][cc] = fmaf(bd[rr], bu[cc], acc[rr][cc]);
        }
    }

    float rmin[8], rmax[8];
#pragma unroll
    for (int rr = 0; rr < 8; ++rr) { rmin[rr] = 3.0e38f; rmax[rr] = -3.0e38f; }
#pragma unroll
    for (int rr = 0; rr < 8; ++rr) {
        size_t gr = (size_t)(row0 + ty * 8 + rr);
#pragma unroll
        for (int cc = 0; cc < 8; ++cc) {
            size_t gc = (size_t)(col0 + tx + 32 * cc);
            float w = Wg[gr * K_IN + gc] + acc[rr][cc];
            wq[gr * K_IN + gc] = w;
            rmin[rr] = fminf(rmin[rr], w);
            rmax[rr] = fmaxf(rmax[rr], w);
        }
    }
    // reduce across the 32 tx lanes (xor over bits 0..4 stays inside each half-wave)
#pragma unroll
    for (int off = 16; off >= 1; off >>= 1) {
#pragma unroll
        for (int rr = 0; rr < 8; ++rr) {
            rmin[rr] = fminf(rmin[rr], __shfl_xor(rmin[rr], off, 64));
            rmax[rr] = fmaxf(rmax[rr], __shfl_xor(rmax[rr], off, 64));
        }
    }
    if (tx == 0) {
#pragma unroll
        for (int rr = 0; rr < 8; ++rr) {
            int gr = row0 + ty * 8 + rr;
            pmin[(size_t)gr * 16 + blockIdx.y] = rmin[rr];
            pmax[(size_t)gr * 16 + blockIdx.y] = rmax[rr];
        }
    }
}

// ---------------------------------------------------------------------------
// Pass 2: per-row scale / zero-point.
// ---------------------------------------------------------------------------
__global__ __launch_bounds__(256) void k_scale_zero(
    const float* __restrict__ pmin, const float* __restrict__ pmax,
    float* __restrict__ scale, float* __restrict__ zero)
{
    int r = blockIdx.x * 256 + threadIdx.x;
    if (r >= N_OUT) return;
    float mn = 0.0f, mx = 0.0f;   // jnp.minimum(min,0) / maximum(max,0)
#pragma unroll
    for (int i = 0; i < 16; ++i) {
        mn = fminf(mn, pmin[(size_t)r * 16 + i]);
        mx = fmaxf(mx, pmax[(size_t)r * 16 + i]);
    }
    float s = fmaxf((mx - mn) / 15.0f, 1e-8f);
    scale[r] = s;
    zero[r] = rintf(-mn / s);     // v_rndne = half-to-even, matches jnp.round
}

// ---------------------------------------------------------------------------
// Pass 3: fake-quant + cast to bf16.  4 elems/thread, exact grid.
// ---------------------------------------------------------------------------
__global__ __launch_bounds__(256) void k_quant_cast(
    const float* __restrict__ wq, const float* __restrict__ scale,
    const float* __restrict__ zero, unsigned short* __restrict__ wb)
{
    size_t i = ((size_t)blockIdx.x * 256 + threadIdx.x) * 4;
    int r = (int)(i >> 12);                 // / 4096 (row; 4-aligned within row)
    float s = scale[r], z = zero[r];
    float4 v = *(const float4*)(wq + i);
    float in[4] = {v.x, v.y, v.z, v.w};
    unsigned short h[4];
#pragma unroll
    for (int j = 0; j < 4; ++j) {
        float q = rintf(in[j] / s) + z;
        q = fminf(fmaxf(q, 0.0f), 15.0f);
        h[j] = f2bf((q - z) * s);
    }
    unsigned int lo = (unsigned int)h[0] | ((unsigned int)h[1] << 16);
    unsigned int hi = (unsigned int)h[2] | ((unsigned int)h[3] << 16);
    *(unsigned long long*)(wb + i) = ((unsigned long long)hi << 32) | lo;
}

// ---------------------------------------------------------------------------
// Pass 4: x -> bf16.
// ---------------------------------------------------------------------------
__global__ __launch_bounds__(256) void k_cast_x(
    const float* __restrict__ x, unsigned short* __restrict__ xb)
{
    size_t i = ((size_t)blockIdx.x * 256 + threadIdx.x) * 4;
    float4 v = *(const float4*)(x + i);
    unsigned int lo = (unsigned int)f2bf(v.x) | ((unsigned int)f2bf(v.y) << 16);
    unsigned int hi = (unsigned int)f2bf(v.z) | ((unsigned int)f2bf(v.w) << 16);
    *(unsigned long long*)(xb + i) = ((unsigned long long)hi << 32) | lo;
}

// ---------------------------------------------------------------------------
// Pass 5: C[m,n] = sum_k A[m,k]*W[n,k] + bias[n]   (bf16 MFMA, f32 out)
// m97 structure: 128x128 tile, BK=32, global_load_lds(16B), 2-barrier K-loop.
// 4 waves in 2x2; each wave: 4x4 accs of 16x16x32 MFMA.
// grid (8192/128=64, 11008/128=86), block 256.
// ---------------------------------------------------------------------------
__global__ __launch_bounds__(256) void k_gemm(
    const unsigned short* __restrict__ A,   // bf16 bits [M_ROWS][K_IN]
    const unsigned short* __restrict__ W,   // bf16 bits [N_OUT][K_IN]
    const float* __restrict__ bias,
    float* __restrict__ C)                  // [M_ROWS][N_OUT]
{
    __shared__ alignas(16) char lds_a[128 * 64];   // 128 rows x 32 k x 2B
    __shared__ alignas(16) char lds_b[128 * 64];
    const int t    = threadIdx.x;
    const int lane = t & 63;
    const int wave = t >> 6;
    const int wr = wave >> 1, wc = wave & 1;
    const int bm0 = blockIdx.x * 128;
    const int bn0 = blockIdx.y * 128;

    // staging: thread t covers tile bytes [t*16, t*16+16) of rows 0..63 (seg0)
    // and rows 64..127 (seg1). row = t/4, k-elem = (t%4)*8.
    const int sr = t >> 2;
    const int sk = (t & 3) * 8;
    const unsigned short* gA = A + (size_t)(bm0 + sr) * K_IN + sk;
    const unsigned short* gW = W + (size_t)(bn0 + sr) * K_IN + sk;
    char* sA = lds_a + wave * 1024;   // wave-uniform LDS base; HW adds lane*16
    char* sB = lds_b + wave * 1024;

    f32x4 acc[4][4];
    const f32x4 zf = {0.f, 0.f, 0.f, 0.f};
#pragma unroll
    for (int i = 0; i < 4; ++i)
#pragma unroll
        for (int j = 0; j < 4; ++j) acc[i][j] = zf;

    const int lrow = lane & 15, lq = lane >> 4;
    const int aoff = (wr * 64 + lrow) * 64 + lq * 16;   // bytes
    const int boff = (wc * 64 + lrow) * 64 + lq * 16;

    for (int kt = 0; kt < K_IN / 32; ++kt) {
        GLDS16(gA,                      sA);
        GLDS16(gA + (size_t)64 * K_IN,  sA + 4096);
        GLDS16(gW,                      sB);
        GLDS16(gW + (size_t)64 * K_IN,  sB + 4096);
        gA += 32; gW += 32;
        __syncthreads();   // drains vmcnt(0): staging visible to all

        bf16x8 af[4], bfr[4];
#pragma unroll
        for (int mi = 0; mi < 4; ++mi)
            af[mi] = *(const bf16x8*)(lds_a + aoff + mi * 1024);
#pragma unroll
        for (int ni = 0; ni < 4; ++ni)
            bfr[ni] = *(const bf16x8*)(lds_b + boff + ni * 1024);
#pragma unroll
        for (int mi = 0; mi < 4; ++mi)
#pragma unroll
            for (int ni = 0; ni < 4; ++ni)
                acc[mi][ni] = __builtin_amdgcn_mfma_f32_16x16x32_bf16(
                    af[mi], bfr[ni], acc[mi][ni], 0, 0, 0);
        __syncthreads();   // all reads done before next stage overwrites
    }

    // epilogue: C/D layout col = lane&15, row = (lane>>4)*4 + reg  [m89/m91]
#pragma unroll
    for (int mi = 0; mi < 4; ++mi) {
        const int row = bm0 + wr * 64 + mi * 16 + lq * 4;
#pragma unroll
        for (int ni = 0; ni < 4; ++ni) {
            const int col = bn0 + wc * 64 + ni * 16 + lrow;
            const float bb = bias[col];
#pragma unroll
            for (int r = 0; r < 4; ++r)
                C[(size_t)(row + r) * N_OUT + col] = acc[mi][ni][r] + bb;
        }
    }
}

// ---------------------------------------------------------------------------
extern "C" void kernel_launch(void* const* d_in, const int* in_sizes, int n_in,
                              void* d_out, int out_size, void* d_ws, size_t ws_size,
                              hipStream_t stream)
{
    const float* x      = (const float*)d_in[0];   // [4,2048,4096]
    const float* weight = (const float*)d_in[1];   // [11008,4096]
    const float* Bd     = (const float*)d_in[2];   // [11008,192]
    const float* Bu     = (const float*)d_in[3];   // [192,4096]
    const float* bias   = (const float*)d_in[4];   // [11008]
    float* out = (float*)d_out;                    // [8192,11008] f32

    char* ws = (char*)d_ws;
    // ws layout (256B-aligned):
    float*          wq    = (float*)(ws);                      // 180,355,072 B
    float*          pmin  = (float*)(ws + 180355072);          //     704,512 B
    float*          pmax  = (float*)(ws + 181059584);          //     704,512 B
    float*          scale = (float*)(ws + 181764096);          //      44,032 B
    float*          zero  = (float*)(ws + 181808128);          //      44,032 B
    unsigned short* wb    = (unsigned short*)(ws + 181852160); //  90,177,536 B
    unsigned short* xb    = (unsigned short*)(ws + 272029696); //  67,108,864 B
    // total ws use: 339,138,560 B

    k_delta_minmax<<<dim3(N_OUT / 64, K_IN / 256), 256, 0, stream>>>(
        weight, Bd, Bu, wq, pmin, pmax);
    k_scale_zero<<<(N_OUT + 255) / 256, 256, 0, stream>>>(pmin, pmax, scale, zero);
    k_quant_cast<<<(N_OUT * (K_IN / 4)) / 256, 256, 0, stream>>>(wq, scale, zero, wb);
    k_cast_x<<<(M_ROWS * (K_IN / 4)) / 256, 256, 0, stream>>>(x, xb);
    k_gemm<<<dim3(M_ROWS / 128, N_OUT / 128), 256, 0, stream>>>(xb, wb, bias, out);
}